// Round 1
// baseline (715.516 us; speedup 1.0000x reference)
//
#include <hip/hip_runtime.h>
#include <math.h>

#define B 128
#define C 576
#define H 28
#define W 28
#define HW 784
#define NPLANE (B * C)

__device__ __forceinline__ float sigm(float z) { return 1.f / (1.f + __expf(-z)); }

__device__ __forceinline__ float wave_sum(float v) {
#pragma unroll
    for (int m = 32; m > 0; m >>= 1) v += __shfl_xor(v, m, 64);
    return v;
}

// ---------------------------------------------------------------------------
// K0: zero the accumulator array and build the 6 orientation masks.
// ---------------------------------------------------------------------------
__global__ void k0_init(float* __restrict__ masks, float* __restrict__ acc) {
    int idx = blockIdx.x * 256 + threadIdx.x;
    if (idx < 6 * C) acc[idx] = 0.f;
    if (idx < 6 * HW) {
        int a = idx / HW;
        int rem = idx - a * HW;
        int r = rem / W;
        int col = rem - r * W;
        const float degs[6] = {0.f, 30.f, 45.f, 60.f, 90.f, 135.f};
        float t = degs[a] * 0.017453292519943295f;
        float gy = -1.f + r * (2.f / 27.f);
        float gx = -1.f + col * (2.f / 27.f);
        float perp = gx * (-sinf(t)) + gy * cosf(t);
        float z = perp * (1.f / 0.3f);
        masks[idx] = expf(-0.5f * z * z);
    }
}

// ---------------------------------------------------------------------------
// K1: per-plane statistics pass.
//  - row/col means -> depthwise conv3 -> y_h/y_v to ws, per-channel sum/sumsq
//  - separable 7x7 maxpool -> spots stats (sum/sumsq of (max-x)*f_w)
//  - orientation responses -> A_t per plane
// ---------------------------------------------------------------------------
__global__ __launch_bounds__(256) void k1_stats(
    const float* __restrict__ x,
    const float* __restrict__ h_w, const float* __restrict__ v_w,
    const float* __restrict__ f_w, const float* __restrict__ masks,
    float* __restrict__ yh, float* __restrict__ yv,
    float* __restrict__ at, float* __restrict__ acc)
{
    const int plane = blockIdx.x;
    const int c = plane % C;
    const float* xp = x + (size_t)plane * HW;
    __shared__ float sx[HW];
    __shared__ float rm[HW];
    __shared__ float ph[H], pv[W];
    __shared__ float red[8][4];
    const int tid = threadIdx.x;

    if (tid < HW / 4) ((float4*)sx)[tid] = ((const float4*)xp)[tid];
    __syncthreads();

    // orientation partial sums (masks are 18.8KB -> L1 resident)
    float o0 = 0.f, o1 = 0.f, o2 = 0.f, o3 = 0.f, o4 = 0.f, o5 = 0.f;
    for (int idx = tid; idx < HW; idx += 256) {
        float xv = sx[idx];
        o0 += xv * masks[idx];
        o1 += xv * masks[HW + idx];
        o2 += xv * masks[2 * HW + idx];
        o3 += xv * masks[3 * HW + idx];
        o4 += xv * masks[4 * HW + idx];
        o5 += xv * masks[5 * HW + idx];
    }

    // horizontal 7-window max
    for (int idx = tid; idx < HW; idx += 256) {
        int h = idx / W, w = idx - h * W;
        int w0 = max(w - 3, 0), w1 = min(w + 3, W - 1);
        float m = -INFINITY;
        for (int ww = w0; ww <= w1; ++ww) m = fmaxf(m, sx[h * W + ww]);
        rm[idx] = m;
    }

    // row / col means (reads sx only; safe before the sync)
    if (tid < H) {
        float s = 0.f;
        for (int w = 0; w < W; ++w) s += sx[tid * W + w];
        ph[tid] = s * (1.f / (float)W);
    } else if (tid >= 64 && tid < 64 + W) {
        int w = tid - 64;
        float s = 0.f;
        for (int h = 0; h < H; ++h) s += sx[h * W + w];
        pv[w] = s * (1.f / (float)H);
    }
    __syncthreads();

    // vertical 7-window max -> spots stats
    float fs = 0.f, fss = 0.f;
    const float fwc = f_w[c];
    for (int idx = tid; idx < HW; idx += 256) {
        int h = idx / W, w = idx - h * W;
        int h0 = max(h - 3, 0), h1 = min(h + 3, H - 1);
        float m = -INFINITY;
        for (int hh = h0; hh <= h1; ++hh) m = fmaxf(m, rm[hh * W + w]);
        float s = (m - sx[idx]) * fwc;
        fs += s;
        fss += s * s;
    }

    // depthwise conv3 (cross-correlation, zero 'SAME' padding) + per-plane sums
    float ya = 0.f, ys2 = 0.f;
    if (tid < 64) {
        float y = 0.f;
        if (tid < H) {
            float a = (tid > 0) ? ph[tid - 1] : 0.f;
            float b = ph[tid];
            float d = (tid < H - 1) ? ph[tid + 1] : 0.f;
            y = h_w[c * 3] * a + h_w[c * 3 + 1] * b + h_w[c * 3 + 2] * d;
            yh[(size_t)plane * H + tid] = y;
        }
        ya = y; ys2 = y * y;
    } else if (tid < 128) {
        int w = tid - 64;
        float y = 0.f;
        if (w < W) {
            float a = (w > 0) ? pv[w - 1] : 0.f;
            float b = pv[w];
            float d = (w < W - 1) ? pv[w + 1] : 0.f;
            y = v_w[c * 3] * a + v_w[c * 3 + 1] * b + v_w[c * 3 + 2] * d;
            yv[(size_t)plane * W + w] = y;
        }
        ya = y; ys2 = y * y;
    }
    float ry = wave_sum(ya);    // wave0: h-sum, wave1: v-sum
    float rys = wave_sum(ys2);
    if (tid == 0)  { atomicAdd(&acc[0 * C + c], ry); atomicAdd(&acc[1 * C + c], rys); }
    if (tid == 64) { atomicAdd(&acc[2 * C + c], ry); atomicAdd(&acc[3 * C + c], rys); }

    // block reduce: 6 orientation sums + f sum/sumsq
    const int wv = tid >> 6;
    const int ln = tid & 63;
    float r;
    r = wave_sum(o0); if (ln == 0) red[0][wv] = r;
    r = wave_sum(o1); if (ln == 0) red[1][wv] = r;
    r = wave_sum(o2); if (ln == 0) red[2][wv] = r;
    r = wave_sum(o3); if (ln == 0) red[3][wv] = r;
    r = wave_sum(o4); if (ln == 0) red[4][wv] = r;
    r = wave_sum(o5); if (ln == 0) red[5][wv] = r;
    r = wave_sum(fs); if (ln == 0) red[6][wv] = r;
    r = wave_sum(fss); if (ln == 0) red[7][wv] = r;
    __syncthreads();
    if (tid == 0) {
        float t = 0.f;
        #pragma unroll
        for (int a = 0; a < 6; ++a) {
            float resp = red[a][0] + red[a][1] + red[a][2] + red[a][3];
            t += sigm(resp * (1.f / (float)HW));
        }
        at[plane] = t * (1.f / 6.f);
        float F = red[6][0] + red[6][1] + red[6][2] + red[6][3];
        float FS = red[7][0] + red[7][1] + red[7][2] + red[7][3];
        atomicAdd(&acc[4 * C + c], F);
        atomicAdd(&acc[5 * C + c], FS);
    }
}

// ---------------------------------------------------------------------------
// K2: fold sums into per-channel BN scale/shift (training-mode, biased var).
// ---------------------------------------------------------------------------
__global__ void k2_params(const float* __restrict__ acc,
                          const float* __restrict__ hg, const float* __restrict__ hb,
                          const float* __restrict__ vg, const float* __restrict__ vb,
                          const float* __restrict__ fg, const float* __restrict__ fb,
                          float* __restrict__ params)
{
    int c = blockIdx.x * blockDim.x + threadIdx.x;
    if (c >= C) return;
    const float inv_nh = 1.f / (float)(B * H);
    const float inv_nf = 1.f / (float)(B * HW);
    float m, v, sc;
    m = acc[c] * inv_nh;
    v = acc[C + c] * inv_nh - m * m;
    sc = hg[c] * rsqrtf(v + 1e-5f);
    params[c] = sc; params[C + c] = hb[c] - m * sc;

    m = acc[2 * C + c] * inv_nh;
    v = acc[3 * C + c] * inv_nh - m * m;
    sc = vg[c] * rsqrtf(v + 1e-5f);
    params[2 * C + c] = sc; params[3 * C + c] = vb[c] - m * sc;

    m = acc[4 * C + c] * inv_nf;
    v = acc[5 * C + c] * inv_nf - m * m;
    sc = fg[c] * rsqrtf(v + 1e-5f);
    params[4 * C + c] = sc; params[5 * C + c] = fb[c] - m * sc;
}

// ---------------------------------------------------------------------------
// K3: apply all four gates; recompute the separable maxpool from LDS.
// ---------------------------------------------------------------------------
__global__ __launch_bounds__(256) void k3_apply(
    const float* __restrict__ x, const float* __restrict__ f_w,
    const float* __restrict__ yh, const float* __restrict__ yv,
    const float* __restrict__ at, const float* __restrict__ params,
    float* __restrict__ out)
{
    const int plane = blockIdx.x;
    const int c = plane % C;
    const float* xp = x + (size_t)plane * HW;
    __shared__ float sx[HW];
    __shared__ float rm[HW];
    __shared__ float ah[H], av[W];
    const int tid = threadIdx.x;

    if (tid < HW / 4) ((float4*)sx)[tid] = ((const float4*)xp)[tid];
    if (tid >= 224 && tid < 224 + H) {
        int h = tid - 224;
        ah[h] = sigm(params[c] * yh[(size_t)plane * H + h] + params[C + c]);
    }
    if (tid >= 196 && tid < 196 + W) {
        int w = tid - 196;
        av[w] = sigm(params[2 * C + c] * yv[(size_t)plane * W + w] + params[3 * C + c]);
    }
    __syncthreads();

    for (int idx = tid; idx < HW; idx += 256) {
        int h = idx / W, w = idx - h * W;
        int w0 = max(w - 3, 0), w1 = min(w + 3, W - 1);
        float m = -INFINITY;
        for (int ww = w0; ww <= w1; ++ww) m = fmaxf(m, sx[h * W + ww]);
        rm[idx] = m;
    }
    __syncthreads();

    const float fsc = params[4 * C + c];
    const float fsh = params[5 * C + c];
    const float fwc = f_w[c];
    const float atv = at[plane];
    for (int idx = tid; idx < HW; idx += 256) {
        int h = idx / W, w = idx - h * W;
        int h0 = max(h - 3, 0), h1 = min(h + 3, H - 1);
        float m = -INFINITY;
        for (int hh = h0; hh <= h1; ++hh) m = fmaxf(m, rm[hh * W + w]);
        float s = (m - sx[idx]) * fwc;
        float af = sigm(fsc * s + fsh);
        out[(size_t)plane * HW + idx] = sx[idx] * ah[h] * av[w] * af * atv;
    }
}

// ---------------------------------------------------------------------------
extern "C" void kernel_launch(void* const* d_in, const int* in_sizes, int n_in,
                              void* d_out, int out_size, void* d_ws, size_t ws_size,
                              hipStream_t stream) {
    const float* x   = (const float*)d_in[0];
    const float* h_w = (const float*)d_in[1];
    const float* h_g = (const float*)d_in[2];
    const float* h_b = (const float*)d_in[3];
    const float* v_w = (const float*)d_in[4];
    const float* v_g = (const float*)d_in[5];
    const float* v_b = (const float*)d_in[6];
    const float* f_w = (const float*)d_in[7];
    const float* f_g = (const float*)d_in[8];
    const float* f_b = (const float*)d_in[9];
    float* out = (float*)d_out;
    float* ws = (float*)d_ws;

    // workspace layout (floats)
    float* masks  = ws;                    // 6*784           = 4704
    float* acc    = ws + 4704;             // 6*576           = 3456
    float* params = ws + 8160;             // 6*576           = 3456
    float* at     = ws + 11616;            // B*C             = 73728
    float* yh     = ws + 85344;            // B*C*H           = 2064384
    float* yv     = ws + 2149728;          // B*C*W           = 2064384
    // total: 4214112 floats = 16.9 MB

    k0_init<<<19, 256, 0, stream>>>(masks, acc);
    k1_stats<<<NPLANE, 256, 0, stream>>>(x, h_w, v_w, f_w, masks, yh, yv, at, acc);
    k2_params<<<(C + 191) / 192, 192, 0, stream>>>(acc, h_g, h_b, v_g, v_b, f_g, f_b, params);
    k3_apply<<<NPLANE, 256, 0, stream>>>(x, f_w, yh, yv, at, params, out);
}

// Round 2
// 321.647 us; speedup vs baseline: 2.2245x; 2.2245x over previous
//
#include <hip/hip_runtime.h>
#include <math.h>

#define B 128
#define C 576
#define H 28
#define W 28
#define HW 784
#define NPLANE (B * C)

__device__ __forceinline__ float sigm(float z) { return 1.f / (1.f + __expf(-z)); }

__device__ __forceinline__ float wave_sum(float v) {
#pragma unroll
    for (int m = 32; m > 0; m >>= 1) v += __shfl_xor(v, m, 64);
    return v;
}

// ---------------------------------------------------------------------------
// K0: zero the accumulator array and build the 6 orientation masks.
// ---------------------------------------------------------------------------
__global__ void k0_init(float* __restrict__ masks, float* __restrict__ acc) {
    int idx = blockIdx.x * 256 + threadIdx.x;
    if (idx < 6 * C) acc[idx] = 0.f;
    if (idx < 6 * HW) {
        int a = idx / HW;
        int rem = idx - a * HW;
        int r = rem / W;
        int col = rem - r * W;
        const float degs[6] = {0.f, 30.f, 45.f, 60.f, 90.f, 135.f};
        float t = degs[a] * 0.017453292519943295f;
        float gy = -1.f + r * (2.f / 27.f);
        float gx = -1.f + col * (2.f / 27.f);
        float perp = gx * (-sinf(t)) + gy * cosf(t);
        float z = perp * (1.f / 0.3f);
        masks[idx] = expf(-0.5f * z * z);
    }
}

// ---------------------------------------------------------------------------
// K1: per-plane statistics pass (unrolled clamped pooling, fused passes).
// ---------------------------------------------------------------------------
__global__ __launch_bounds__(256) void k1_stats(
    const float* __restrict__ x,
    const float* __restrict__ h_w, const float* __restrict__ v_w,
    const float* __restrict__ f_w, const float* __restrict__ masks,
    float* __restrict__ yh, float* __restrict__ yv,
    float* __restrict__ at, float* __restrict__ acc)
{
    const int plane = blockIdx.x;
    const int c = plane % C;
    const float* xp = x + (size_t)plane * HW;
    __shared__ float sx[HW];
    __shared__ float rm[HW];
    __shared__ float ph[H], pv[W];
    __shared__ float red2[8][257];
    const int tid = threadIdx.x;

    if (tid < 196) ((float4*)sx)[tid] = ((const float4*)xp)[tid];
    __syncthreads();

    // per-thread pixel coords (computed once)
    const int h0 = tid / W,              w0 = tid - h0 * W;
    const int p1 = tid + 256; const int h1 = p1 / W, w1 = p1 - h1 * W;
    const int p2 = tid + 512; const int h2 = p2 / W, w2 = p2 - h2 * W;
    const int w3 = tid + 12;  // tail pixels 768..783 all in row 27 (tid<16)

    float o0=0.f,o1=0.f,o2=0.f,o3=0.f,o4=0.f,o5=0.f;

    // pass 1: orientation partials + horizontal 7-window max (unrolled, clamped)
    auto pass1 = [&](int h, int w, int idx) {
        float xv = sx[idx];
        o0 += xv * masks[idx];
        o1 += xv * masks[HW + idx];
        o2 += xv * masks[2 * HW + idx];
        o3 += xv * masks[3 * HW + idx];
        o4 += xv * masks[4 * HW + idx];
        o5 += xv * masks[5 * HW + idx];
        const float* row = sx + h * W;
        float m = row[max(w - 3, 0)];
        m = fmaxf(m, row[max(w - 2, 0)]);
        m = fmaxf(m, row[max(w - 1, 0)]);
        m = fmaxf(m, row[w]);
        m = fmaxf(m, row[min(w + 1, W - 1)]);
        m = fmaxf(m, row[min(w + 2, W - 1)]);
        m = fmaxf(m, row[min(w + 3, W - 1)]);
        rm[idx] = m;
    };
    pass1(h0, w0, tid);
    pass1(h1, w1, p1);
    pass1(h2, w2, p2);
    if (tid < 16) pass1(H - 1, w3, tid + 768);

    // row / col means (reads sx only)
    if (tid < H) {
        const float* row = sx + tid * W;
        float s = 0.f;
        #pragma unroll
        for (int w = 0; w < W; ++w) s += row[w];
        ph[tid] = s * (1.f / (float)W);
    } else if (tid >= 64 && tid < 64 + W) {
        int w = tid - 64;
        float s = 0.f;
        #pragma unroll
        for (int h = 0; h < H; ++h) s += sx[h * W + w];
        pv[w] = s * (1.f / (float)H);
    }
    __syncthreads();

    // pass 2: vertical 7-window max (unrolled, clamped) -> spots stats
    float fs = 0.f, fss = 0.f;
    const float fwc = f_w[c];
    auto pass2 = [&](int h, int w, int idx) {
        float m = rm[max(h - 3, 0) * W + w];
        m = fmaxf(m, rm[max(h - 2, 0) * W + w]);
        m = fmaxf(m, rm[max(h - 1, 0) * W + w]);
        m = fmaxf(m, rm[h * W + w]);
        m = fmaxf(m, rm[min(h + 1, H - 1) * W + w]);
        m = fmaxf(m, rm[min(h + 2, H - 1) * W + w]);
        m = fmaxf(m, rm[min(h + 3, H - 1) * W + w]);
        float s = (m - sx[idx]) * fwc;
        fs += s;
        fss += s * s;
    };
    pass2(h0, w0, tid);
    pass2(h1, w1, p1);
    pass2(h2, w2, p2);
    if (tid < 16) pass2(H - 1, w3, tid + 768);

    // depthwise conv3 + per-wave BN partial sums (waves 0-1 only; wave-uniform)
    if (tid < 128) {
        float y = 0.f;
        if (tid < H) {
            float a = (tid > 0) ? ph[tid - 1] : 0.f;
            float bb = ph[tid];
            float d = (tid < H - 1) ? ph[tid + 1] : 0.f;
            y = h_w[c * 3] * a + h_w[c * 3 + 1] * bb + h_w[c * 3 + 2] * d;
            yh[(size_t)plane * H + tid] = y;
        } else if (tid >= 64 && tid < 64 + W) {
            int w = tid - 64;
            float a = (w > 0) ? pv[w - 1] : 0.f;
            float bb = pv[w];
            float d = (w < W - 1) ? pv[w + 1] : 0.f;
            y = v_w[c * 3] * a + v_w[c * 3 + 1] * bb + v_w[c * 3 + 2] * d;
            yv[(size_t)plane * W + w] = y;
        }
        float ry = wave_sum(y);
        float rys = wave_sum(y * y);
        if (tid == 0)  { atomicAdd(&acc[0 * C + c], ry); atomicAdd(&acc[1 * C + c], rys); }
        if (tid == 64) { atomicAdd(&acc[2 * C + c], ry); atomicAdd(&acc[3 * C + c], rys); }
    }

    // two-stage LDS reduction: 6 orientation sums + f sum/sumsq
    red2[0][tid] = o0; red2[1][tid] = o1; red2[2][tid] = o2; red2[3][tid] = o3;
    red2[4][tid] = o4; red2[5][tid] = o5; red2[6][tid] = fs; red2[7][tid] = fss;
    __syncthreads();
    {
        const int q = tid >> 5, j = tid & 31;
        const float* r = red2[q];
        float s = r[j] + r[j + 32] + r[j + 64] + r[j + 96]
                + r[j + 128] + r[j + 160] + r[j + 192] + r[j + 224];
        #pragma unroll
        for (int m = 16; m > 0; m >>= 1) s += __shfl_xor(s, m, 64);
        if (j == 0) red2[q][256] = s;
    }
    __syncthreads();
    if (tid == 0) {
        float t = 0.f;
        #pragma unroll
        for (int a = 0; a < 6; ++a) t += sigm(red2[a][256] * (1.f / (float)HW));
        at[plane] = t * (1.f / 6.f);
        atomicAdd(&acc[4 * C + c], red2[6][256]);
        atomicAdd(&acc[5 * C + c], red2[7][256]);
    }
}

// ---------------------------------------------------------------------------
// K2: fold sums into per-channel BN scale/shift (training-mode, biased var).
// ---------------------------------------------------------------------------
__global__ void k2_params(const float* __restrict__ acc,
                          const float* __restrict__ hg, const float* __restrict__ hb,
                          const float* __restrict__ vg, const float* __restrict__ vb,
                          const float* __restrict__ fg, const float* __restrict__ fb,
                          float* __restrict__ params)
{
    int c = blockIdx.x * blockDim.x + threadIdx.x;
    if (c >= C) return;
    const float inv_nh = 1.f / (float)(B * H);
    const float inv_nf = 1.f / (float)(B * HW);
    float m, v, sc;
    m = acc[c] * inv_nh;
    v = acc[C + c] * inv_nh - m * m;
    sc = hg[c] * rsqrtf(v + 1e-5f);
    params[c] = sc; params[C + c] = hb[c] - m * sc;

    m = acc[2 * C + c] * inv_nh;
    v = acc[3 * C + c] * inv_nh - m * m;
    sc = vg[c] * rsqrtf(v + 1e-5f);
    params[2 * C + c] = sc; params[3 * C + c] = vb[c] - m * sc;

    m = acc[4 * C + c] * inv_nf;
    v = acc[5 * C + c] * inv_nf - m * m;
    sc = fg[c] * rsqrtf(v + 1e-5f);
    params[4 * C + c] = sc; params[5 * C + c] = fb[c] - m * sc;
}

// ---------------------------------------------------------------------------
// K3: apply all four gates; recompute the separable maxpool (unrolled).
// ---------------------------------------------------------------------------
__global__ __launch_bounds__(256) void k3_apply(
    const float* __restrict__ x, const float* __restrict__ f_w,
    const float* __restrict__ yh, const float* __restrict__ yv,
    const float* __restrict__ at, const float* __restrict__ params,
    float* __restrict__ out)
{
    const int plane = blockIdx.x;
    const int c = plane % C;
    const float* xp = x + (size_t)plane * HW;
    __shared__ float sx[HW];
    __shared__ float rm[HW];
    __shared__ float ah[H], av[W];
    const int tid = threadIdx.x;

    if (tid < 196) {
        ((float4*)sx)[tid] = ((const float4*)xp)[tid];
    } else if (tid >= 196 && tid < 196 + W) {
        int w = tid - 196;
        av[w] = sigm(params[2 * C + c] * yv[(size_t)plane * W + w] + params[3 * C + c]);
    } else if (tid >= 224 && tid < 224 + H) {
        int h = tid - 224;
        ah[h] = sigm(params[c] * yh[(size_t)plane * H + h] + params[C + c]);
    }
    __syncthreads();

    const int h0 = tid / W,              w0 = tid - h0 * W;
    const int p1 = tid + 256; const int h1 = p1 / W, w1 = p1 - h1 * W;
    const int p2 = tid + 512; const int h2 = p2 / W, w2 = p2 - h2 * W;
    const int w3 = tid + 12;

    auto hmax = [&](int h, int w, int idx) {
        const float* row = sx + h * W;
        float m = row[max(w - 3, 0)];
        m = fmaxf(m, row[max(w - 2, 0)]);
        m = fmaxf(m, row[max(w - 1, 0)]);
        m = fmaxf(m, row[w]);
        m = fmaxf(m, row[min(w + 1, W - 1)]);
        m = fmaxf(m, row[min(w + 2, W - 1)]);
        m = fmaxf(m, row[min(w + 3, W - 1)]);
        rm[idx] = m;
    };
    hmax(h0, w0, tid);
    hmax(h1, w1, p1);
    hmax(h2, w2, p2);
    if (tid < 16) hmax(H - 1, w3, tid + 768);
    __syncthreads();

    const float fsc = params[4 * C + c];
    const float fsh = params[5 * C + c];
    const float fwc = f_w[c];
    const float atv = at[plane];
    float* op = out + (size_t)plane * HW;

    auto emit = [&](int h, int w, int idx) {
        float m = rm[max(h - 3, 0) * W + w];
        m = fmaxf(m, rm[max(h - 2, 0) * W + w]);
        m = fmaxf(m, rm[max(h - 1, 0) * W + w]);
        m = fmaxf(m, rm[h * W + w]);
        m = fmaxf(m, rm[min(h + 1, H - 1) * W + w]);
        m = fmaxf(m, rm[min(h + 2, H - 1) * W + w]);
        m = fmaxf(m, rm[min(h + 3, H - 1) * W + w]);
        float xv = sx[idx];
        float s = (m - xv) * fwc;
        float af = sigm(fsc * s + fsh);
        op[idx] = xv * ah[h] * av[w] * af * atv;
    };
    emit(h0, w0, tid);
    emit(h1, w1, p1);
    emit(h2, w2, p2);
    if (tid < 16) emit(H - 1, w3, tid + 768);
}

// ---------------------------------------------------------------------------
extern "C" void kernel_launch(void* const* d_in, const int* in_sizes, int n_in,
                              void* d_out, int out_size, void* d_ws, size_t ws_size,
                              hipStream_t stream) {
    const float* x   = (const float*)d_in[0];
    const float* h_w = (const float*)d_in[1];
    const float* h_g = (const float*)d_in[2];
    const float* h_b = (const float*)d_in[3];
    const float* v_w = (const float*)d_in[4];
    const float* v_g = (const float*)d_in[5];
    const float* v_b = (const float*)d_in[6];
    const float* f_w = (const float*)d_in[7];
    const float* f_g = (const float*)d_in[8];
    const float* f_b = (const float*)d_in[9];
    float* out = (float*)d_out;
    float* ws = (float*)d_ws;

    // workspace layout (floats)
    float* masks  = ws;                    // 6*784           = 4704
    float* acc    = ws + 4704;             // 6*576           = 3456
    float* params = ws + 8160;             // 6*576           = 3456
    float* at     = ws + 11616;            // B*C             = 73728
    float* yh     = ws + 85344;            // B*C*H           = 2064384
    float* yv     = ws + 2149728;          // B*C*W           = 2064384

    k0_init<<<19, 256, 0, stream>>>(masks, acc);
    k1_stats<<<NPLANE, 256, 0, stream>>>(x, h_w, v_w, f_w, masks, yh, yv, at, acc);
    k2_params<<<(C + 191) / 192, 192, 0, stream>>>(acc, h_g, h_b, v_g, v_b, f_g, f_b, params);
    k3_apply<<<NPLANE, 256, 0, stream>>>(x, f_w, yh, yv, at, params, out);
}

// Round 3
// 304.197 us; speedup vs baseline: 2.3522x; 1.0574x over previous
//
#include <hip/hip_runtime.h>
#include <math.h>

#define B 128
#define C 576
#define H 28
#define W 28
#define HW 784
#define NPLANE (B * C)
#define NU 196  // float4 units per plane (784/4)

__device__ __forceinline__ float sigm(float z) { return 1.f / (1.f + __expf(-z)); }
__device__ __forceinline__ float max3f(float a, float b, float c) { return fmaxf(fmaxf(a, b), c); }

__device__ __forceinline__ float wave_sum(float v) {
#pragma unroll
    for (int m = 32; m > 0; m >>= 1) v += __shfl_xor(v, m, 64);
    return v;
}

__device__ __forceinline__ float4 fmax4(float4 a, float4 b) {
    a.x = fmaxf(a.x, b.x); a.y = fmaxf(a.y, b.y);
    a.z = fmaxf(a.z, b.z); a.w = fmaxf(a.w, b.w);
    return a;
}

// horizontal 7-window max for 4 consecutive pixels (cols q..q+3); Mv = row[q..q+3]
__device__ __forceinline__ float4 hmax_unit(const float* row, int q, float4 Mv) {
    float4 Lv = *(const float4*)(row + (q ? q - 4 : q));          // clamp: dup values ok under max
    float4 Rv = *(const float4*)(row + (q < W - 4 ? q + 4 : q));
    float mm   = fmaxf(fmaxf(Mv.x, Mv.y), fmaxf(Mv.z, Mv.w));
    float l23  = fmaxf(Lv.z, Lv.w);
    float l123 = fmaxf(Lv.y, l23);
    float r01  = fmaxf(Rv.x, Rv.y);
    float r012 = fmaxf(r01, Rv.z);
    float4 o;
    o.x = fmaxf(l123, mm);        // cols q-3..q+3
    o.y = max3f(l23, mm, Rv.x);   // cols q-2..q+4
    o.z = max3f(Lv.w, mm, r01);   // cols q-1..q+5
    o.w = fmaxf(mm, r012);        // cols q  ..q+6
    return o;
}

// vertical 7-window max over rm at rows h-3..h+3 (clamped), cols q..q+3
__device__ __forceinline__ float4 vmax_unit(const float* rmp, int h, int q) {
    const float* cb = rmp + q;
    float4 m = *(const float4*)(cb + h * W);
    m = fmax4(m, *(const float4*)(cb + max(h - 3, 0) * W));
    m = fmax4(m, *(const float4*)(cb + max(h - 2, 0) * W));
    m = fmax4(m, *(const float4*)(cb + max(h - 1, 0) * W));
    m = fmax4(m, *(const float4*)(cb + min(h + 1, H - 1) * W));
    m = fmax4(m, *(const float4*)(cb + min(h + 2, H - 1) * W));
    m = fmax4(m, *(const float4*)(cb + min(h + 3, H - 1) * W));
    return m;
}

// ---------------------------------------------------------------------------
// K0: zero accumulators and build the 6 orientation masks.
// ---------------------------------------------------------------------------
__global__ void k0_init(float* __restrict__ masks, float* __restrict__ acc) {
    int idx = blockIdx.x * 256 + threadIdx.x;
    if (idx < 6 * C) acc[idx] = 0.f;
    if (idx < 6 * HW) {
        int a = idx / HW;
        int rem = idx - a * HW;
        int r = rem / W;
        int col = rem - r * W;
        const float degs[6] = {0.f, 30.f, 45.f, 60.f, 90.f, 135.f};
        float t = degs[a] * 0.017453292519943295f;
        float gy = -1.f + r * (2.f / 27.f);
        float gx = -1.f + col * (2.f / 27.f);
        float perp = gx * (-sinf(t)) + gy * cosf(t);
        float z = perp * (1.f / 0.3f);
        masks[idx] = expf(-0.5f * z * z);
    }
}

// ---------------------------------------------------------------------------
// K1: per-plane statistics pass (float4 units).
// ---------------------------------------------------------------------------
__global__ __launch_bounds__(256) void k1_stats(
    const float* __restrict__ x,
    const float* __restrict__ h_w, const float* __restrict__ v_w,
    const float* __restrict__ f_w, const float* __restrict__ masks,
    float* __restrict__ yh, float* __restrict__ yv,
    float* __restrict__ at, float* __restrict__ acc)
{
    const int plane = blockIdx.x;
    const int c = plane % C;
    const float* xp = x + (size_t)plane * HW;
    __shared__ __align__(16) float sx[HW];
    __shared__ __align__(16) float rm[HW];
    __shared__ float ph[H], pv[W];
    __shared__ float red2[8][257];
    const int tid = threadIdx.x;

    if (tid < NU) ((float4*)sx)[tid] = ((const float4*)xp)[tid];
    __syncthreads();

    const int hrow = tid / 7;
    const int q = (tid - hrow * 7) * 4;

    float o0 = 0.f, o1 = 0.f, o2 = 0.f, o3 = 0.f, o4 = 0.f, o5 = 0.f;
    float fs = 0.f, fss = 0.f;
    float4 Mv;

    // phase A: orientation partials + horizontal max -> rm; spare threads: means
    if (tid < NU) {
        const float* row = sx + hrow * W;
        const int moff = hrow * W + q;
        Mv = *(const float4*)(row + q);
        float4 mk;
        mk = *(const float4*)(masks + moff);
        o0 = Mv.x * mk.x + Mv.y * mk.y + Mv.z * mk.z + Mv.w * mk.w;
        mk = *(const float4*)(masks + HW + moff);
        o1 = Mv.x * mk.x + Mv.y * mk.y + Mv.z * mk.z + Mv.w * mk.w;
        mk = *(const float4*)(masks + 2 * HW + moff);
        o2 = Mv.x * mk.x + Mv.y * mk.y + Mv.z * mk.z + Mv.w * mk.w;
        mk = *(const float4*)(masks + 3 * HW + moff);
        o3 = Mv.x * mk.x + Mv.y * mk.y + Mv.z * mk.z + Mv.w * mk.w;
        mk = *(const float4*)(masks + 4 * HW + moff);
        o4 = Mv.x * mk.x + Mv.y * mk.y + Mv.z * mk.z + Mv.w * mk.w;
        mk = *(const float4*)(masks + 5 * HW + moff);
        o5 = Mv.x * mk.x + Mv.y * mk.y + Mv.z * mk.z + Mv.w * mk.w;
        float4 hv = hmax_unit(row, q, Mv);
        *(float4*)(rm + moff) = hv;
    } else if (tid < NU + W) {
        int cc = tid - NU;
        float s = 0.f;
        #pragma unroll
        for (int h = 0; h < H; ++h) s += sx[h * W + cc];
        pv[cc] = s * (1.f / (float)H);
    } else if (tid < NU + W + H) {
        int r = tid - NU - W;
        const float4* rw = (const float4*)(sx + r * W);
        float s = 0.f;
        #pragma unroll
        for (int k = 0; k < 7; ++k) {
            float4 v = rw[k];
            s += (v.x + v.y) + (v.z + v.w);
        }
        ph[r] = s * (1.f / (float)W);
    }
    __syncthreads();

    // phase B: vertical max -> spots stats
    if (tid < NU) {
        float4 m4 = vmax_unit(rm, hrow, q);
        const float fwc = f_w[c];
        float s0 = (m4.x - Mv.x) * fwc;
        float s1 = (m4.y - Mv.y) * fwc;
        float s2 = (m4.z - Mv.z) * fwc;
        float s3 = (m4.w - Mv.w) * fwc;
        fs  = (s0 + s1) + (s2 + s3);
        fss = (s0 * s0 + s1 * s1) + (s2 * s2 + s3 * s3);
    }

    // depthwise conv3 + BN partial sums (waves 0-1, wave-uniform branch)
    if (tid < 128) {
        float y = 0.f;
        if (tid < H) {
            float a = (tid > 0) ? ph[tid - 1] : 0.f;
            float bb = ph[tid];
            float d = (tid < H - 1) ? ph[tid + 1] : 0.f;
            y = h_w[c * 3] * a + h_w[c * 3 + 1] * bb + h_w[c * 3 + 2] * d;
            yh[(size_t)plane * H + tid] = y;
        } else if (tid >= 64 && tid < 64 + W) {
            int w = tid - 64;
            float a = (w > 0) ? pv[w - 1] : 0.f;
            float bb = pv[w];
            float d = (w < W - 1) ? pv[w + 1] : 0.f;
            y = v_w[c * 3] * a + v_w[c * 3 + 1] * bb + v_w[c * 3 + 2] * d;
            yv[(size_t)plane * W + w] = y;
        }
        float ry = wave_sum(y);
        float rys = wave_sum(y * y);
        if (tid == 0)  { atomicAdd(&acc[0 * C + c], ry); atomicAdd(&acc[1 * C + c], rys); }
        if (tid == 64) { atomicAdd(&acc[2 * C + c], ry); atomicAdd(&acc[3 * C + c], rys); }
    }

    // two-stage LDS reduction: 6 orientation sums + f sum/sumsq
    red2[0][tid] = o0; red2[1][tid] = o1; red2[2][tid] = o2; red2[3][tid] = o3;
    red2[4][tid] = o4; red2[5][tid] = o5; red2[6][tid] = fs; red2[7][tid] = fss;
    __syncthreads();
    {
        const int g = tid >> 5, j = tid & 31;
        const float* r = red2[g];
        float s = ((r[j] + r[j + 32]) + (r[j + 64] + r[j + 96]))
                + ((r[j + 128] + r[j + 160]) + (r[j + 192] + r[j + 224]));
        #pragma unroll
        for (int m = 16; m > 0; m >>= 1) s += __shfl_xor(s, m, 64);
        if (j == 0) red2[g][256] = s;
    }
    __syncthreads();
    if (tid == 0) {
        float t = 0.f;
        #pragma unroll
        for (int a = 0; a < 6; ++a) t += sigm(red2[a][256] * (1.f / (float)HW));
        at[plane] = t * (1.f / 6.f);
        atomicAdd(&acc[4 * C + c], red2[6][256]);
        atomicAdd(&acc[5 * C + c], red2[7][256]);
    }
}

// ---------------------------------------------------------------------------
// K3: fold BN params per block and apply all four gates (float4 units).
// ---------------------------------------------------------------------------
__global__ __launch_bounds__(256) void k3_apply(
    const float* __restrict__ x, const float* __restrict__ f_w,
    const float* __restrict__ yh, const float* __restrict__ yv,
    const float* __restrict__ at, const float* __restrict__ acc,
    const float* __restrict__ hg, const float* __restrict__ hb,
    const float* __restrict__ vg, const float* __restrict__ vb,
    const float* __restrict__ fg, const float* __restrict__ fb,
    float* __restrict__ out)
{
    const int plane = blockIdx.x;
    const int c = plane % C;
    const float* xp = x + (size_t)plane * HW;
    __shared__ __align__(16) float sx[HW];
    __shared__ __align__(16) float rm[HW];
    __shared__ __align__(16) float av[W];
    __shared__ float ah[H];
    __shared__ float fpar[2];
    const int tid = threadIdx.x;
    const float inv_nh = 1.f / (float)(B * H);

    if (tid < NU) {
        ((float4*)sx)[tid] = ((const float4*)xp)[tid];
    } else if (tid < NU + W) {
        int w = tid - NU;
        float m = acc[2 * C + c] * inv_nh;
        float v = acc[3 * C + c] * inv_nh - m * m;
        float sc = vg[c] * rsqrtf(v + 1e-5f);
        float sh = vb[c] - m * sc;
        av[w] = sigm(sc * yv[(size_t)plane * W + w] + sh);
    } else if (tid < NU + W + H) {
        int h = tid - NU - W;
        float m = acc[c] * inv_nh;
        float v = acc[C + c] * inv_nh - m * m;
        float sc = hg[c] * rsqrtf(v + 1e-5f);
        float sh = hb[c] - m * sc;
        ah[h] = sigm(sc * yh[(size_t)plane * H + h] + sh);
    } else if (tid == NU + W + H) {
        const float inv_nf = 1.f / (float)(B * HW);
        float m = acc[4 * C + c] * inv_nf;
        float v = acc[5 * C + c] * inv_nf - m * m;
        float sc = fg[c] * rsqrtf(v + 1e-5f);
        fpar[0] = sc;
        fpar[1] = fb[c] - m * sc;
    }
    __syncthreads();

    const int hrow = tid / 7;
    const int q = (tid - hrow * 7) * 4;
    float4 Mv;
    if (tid < NU) {
        const float* row = sx + hrow * W;
        Mv = *(const float4*)(row + q);
        float4 hv = hmax_unit(row, q, Mv);
        *(float4*)(rm + hrow * W + q) = hv;
    }
    __syncthreads();

    if (tid < NU) {
        float4 m4 = vmax_unit(rm, hrow, q);
        const float fsc = fpar[0], fsh = fpar[1];
        const float fwc = f_w[c];
        const float ga = ah[hrow] * at[plane];
        float4 a4 = *(const float4*)(av + q);
        float4 o;
        o.x = Mv.x * ga * a4.x * sigm(fsc * ((m4.x - Mv.x) * fwc) + fsh);
        o.y = Mv.y * ga * a4.y * sigm(fsc * ((m4.y - Mv.y) * fwc) + fsh);
        o.z = Mv.z * ga * a4.z * sigm(fsc * ((m4.z - Mv.z) * fwc) + fsh);
        o.w = Mv.w * ga * a4.w * sigm(fsc * ((m4.w - Mv.w) * fwc) + fsh);
        ((float4*)(out + (size_t)plane * HW))[tid] = o;
    }
}

// ---------------------------------------------------------------------------
extern "C" void kernel_launch(void* const* d_in, const int* in_sizes, int n_in,
                              void* d_out, int out_size, void* d_ws, size_t ws_size,
                              hipStream_t stream) {
    const float* x   = (const float*)d_in[0];
    const float* h_w = (const float*)d_in[1];
    const float* h_g = (const float*)d_in[2];
    const float* h_b = (const float*)d_in[3];
    const float* v_w = (const float*)d_in[4];
    const float* v_g = (const float*)d_in[5];
    const float* v_b = (const float*)d_in[6];
    const float* f_w = (const float*)d_in[7];
    const float* f_g = (const float*)d_in[8];
    const float* f_b = (const float*)d_in[9];
    float* out = (float*)d_out;
    float* ws = (float*)d_ws;

    // workspace layout (floats)
    float* masks = ws;                 // 6*784
    float* acc   = ws + 4704;          // 6*576
    float* at    = ws + 8160;          // B*C
    float* yh    = ws + 81888;         // B*C*H
    float* yv    = ws + 2146272;       // B*C*W

    k0_init<<<19, 256, 0, stream>>>(masks, acc);
    k1_stats<<<NPLANE, 256, 0, stream>>>(x, h_w, v_w, f_w, masks, yh, yv, at, acc);
    k3_apply<<<NPLANE, 256, 0, stream>>>(x, f_w, yh, yv, at, acc,
                                         h_g, h_b, v_g, v_b, f_g, f_b, out);
}

// Round 4
// 300.778 us; speedup vs baseline: 2.3789x; 1.0114x over previous
//
#include <hip/hip_runtime.h>
#include <math.h>

#define B 128
#define C 576
#define H 28
#define W 28
#define HW 784
#define NPLANE (B * C)
#define NU 196      // float4 units per plane
#define RMROWS 34   // 3 ghost + 28 + 3 ghost

__device__ __forceinline__ float sigm(float z) { return 1.f / (1.f + __expf(-z)); }

__device__ __forceinline__ float wave_sum(float v) {
#pragma unroll
    for (int m = 32; m > 0; m >>= 1) v += __shfl_xor(v, m, 64);
    return v;
}

__device__ __forceinline__ float4 fmax4(float4 a, float4 b) {
    a.x = fmaxf(a.x, b.x); a.y = fmaxf(a.y, b.y);
    a.z = fmaxf(a.z, b.z); a.w = fmaxf(a.w, b.w);
    return a;
}

// horizontal 7-window max for 4 px from Mv (center), Lv (left f4), Rv (right f4)
__device__ __forceinline__ float4 hmax13(float4 Mv, float4 Lv, float4 Rv) {
    float mm   = fmaxf(fmaxf(Mv.x, Mv.y), fmaxf(Mv.z, Mv.w));
    float l23  = fmaxf(Lv.z, Lv.w);
    float l123 = fmaxf(Lv.y, l23);
    float r01  = fmaxf(Rv.x, Rv.y);
    float r012 = fmaxf(r01, Rv.z);
    float4 o;
    o.x = fmaxf(l123, mm);
    o.y = fmaxf(l23, fmaxf(mm, Rv.x));
    o.z = fmaxf(Lv.w, fmaxf(mm, r01));
    o.w = fmaxf(mm, r012);
    return o;
}

// ---------------------------------------------------------------------------
// K0: zero accumulators; build orientation masks interleaved as [196][6][4].
// ---------------------------------------------------------------------------
__global__ void k0_init(float* __restrict__ masks, float* __restrict__ acc) {
    int idx = blockIdx.x * 256 + threadIdx.x;
    if (idx < 6 * C) acc[idx] = 0.f;
    if (idx < 6 * HW) {
        int a = idx / HW;
        int p = idx - a * HW;
        int r = p / W;
        int col = p - r * W;
        const float degs[6] = {0.f, 30.f, 45.f, 60.f, 90.f, 135.f};
        float t = degs[a] * 0.017453292519943295f;
        float gy = -1.f + r * (2.f / 27.f);
        float gx = -1.f + col * (2.f / 27.f);
        float perp = gx * (-sinf(t)) + gy * cosf(t);
        float z = perp * (1.f / 0.3f);
        masks[(p >> 2) * 24 + a * 4 + (p & 3)] = expf(-0.5f * z * z);
    }
}

// ---------------------------------------------------------------------------
// K1: per-plane statistics pass.
// ---------------------------------------------------------------------------
__global__ __launch_bounds__(256, 6) void k1_stats(
    const float* __restrict__ x,
    const float* __restrict__ h_w, const float* __restrict__ v_w,
    const float* __restrict__ f_w, const float* __restrict__ masks,
    float* __restrict__ yh, float* __restrict__ yv,
    float* __restrict__ at, float* __restrict__ acc)
{
    const int plane = blockIdx.x;
    const int c = plane % C;
    const int tid = threadIdx.x;
    const float* xp = x + (size_t)plane * HW;

    __shared__ __align__(16) float sx[HW];
    __shared__ __align__(16) float rm[RMROWS * W];
    __shared__ float rowpart[NU];
    __shared__ float ph[H], pv[W];
    __shared__ float red2[8][257];

    const int hrow = tid / 7;
    const int u = tid - hrow * 7;
    const int q = u * 4;

    float4 Mv;
    if (tid < NU) {
        Mv = ((const float4*)xp)[tid];
        ((float4*)sx)[tid] = Mv;
    }
    __syncthreads();

    float o0 = 0.f, o1 = 0.f, o2 = 0.f, o3 = 0.f, o4 = 0.f, o5 = 0.f;
    float fs = 0.f, fss = 0.f;

    if (tid < NU) {
        const float4* mb = (const float4*)(masks + tid * 24);
        float4 m0 = mb[0], m1 = mb[1], m2 = mb[2], m3 = mb[3], m4 = mb[4], m5 = mb[5];
        o0 = Mv.x * m0.x + Mv.y * m0.y + Mv.z * m0.z + Mv.w * m0.w;
        o1 = Mv.x * m1.x + Mv.y * m1.y + Mv.z * m1.z + Mv.w * m1.w;
        o2 = Mv.x * m2.x + Mv.y * m2.y + Mv.z * m2.z + Mv.w * m2.w;
        o3 = Mv.x * m3.x + Mv.y * m3.y + Mv.z * m3.z + Mv.w * m3.w;
        o4 = Mv.x * m4.x + Mv.y * m4.y + Mv.z * m4.z + Mv.w * m4.w;
        o5 = Mv.x * m5.x + Mv.y * m5.y + Mv.z * m5.z + Mv.w * m5.w;

        const float* row = sx + hrow * W;
        float4 Lv = *(const float4*)(row + (u ? q - 4 : 0));
        float4 Rv = *(const float4*)(row + (u < 6 ? q + 4 : 24));
        float4 hv = hmax13(Mv, Lv, Rv);
        *(float4*)(rm + (hrow + 3) * W + q) = hv;
        if (hrow == 0) {
            *(float4*)(rm + q) = hv;
            *(float4*)(rm + W + q) = hv;
            *(float4*)(rm + 2 * W + q) = hv;
        } else if (hrow == H - 1) {
            *(float4*)(rm + 31 * W + q) = hv;
            *(float4*)(rm + 32 * W + q) = hv;
            *(float4*)(rm + 33 * W + q) = hv;
        }
        rowpart[tid] = (Mv.x + Mv.y) + (Mv.z + Mv.w);
    } else if (tid >= 200) {
        // column half-sums: 56 threads, 14 rows each
        int j = tid - 200;
        int half = (j >= 28);
        int cc = j - (half ? 28 : 0);
        const float* col = sx + cc + (half ? 14 * W : 0);
        float s = 0.f;
        #pragma unroll
        for (int k = 0; k < 14; ++k) s += col[k * W];
        float other = __shfl_down(s, 28, 64);
        if (!half) pv[cc] = (s + other) * (1.f / 28.f);
    }
    __syncthreads();

    if (tid < NU) {
        const float* vb = rm + hrow * W + q;   // padded rows hrow..hrow+6
        float4 m = *(const float4*)vb;
        m = fmax4(m, *(const float4*)(vb + W));
        m = fmax4(m, *(const float4*)(vb + 2 * W));
        m = fmax4(m, *(const float4*)(vb + 3 * W));
        m = fmax4(m, *(const float4*)(vb + 4 * W));
        m = fmax4(m, *(const float4*)(vb + 5 * W));
        m = fmax4(m, *(const float4*)(vb + 6 * W));
        const float fwc = f_w[c];
        float s0 = (m.x - Mv.x) * fwc;
        float s1 = (m.y - Mv.y) * fwc;
        float s2 = (m.z - Mv.z) * fwc;
        float s3 = (m.w - Mv.w) * fwc;
        fs  = (s0 + s1) + (s2 + s3);
        fss = (s0 * s0 + s1 * s1) + (s2 * s2 + s3 * s3);
    } else if (tid >= 228) {
        // assemble row means from unit partials
        int r = tid - 228;
        const float* rp = rowpart + r * 7;
        ph[r] = (((rp[0] + rp[1]) + (rp[2] + rp[3])) + ((rp[4] + rp[5]) + rp[6])) * (1.f / 28.f);
    }

    red2[0][tid] = o0; red2[1][tid] = o1; red2[2][tid] = o2; red2[3][tid] = o3;
    red2[4][tid] = o4; red2[5][tid] = o5; red2[6][tid] = fs; red2[7][tid] = fss;
    __syncthreads();

    // stage-2 reduction (all threads)
    {
        const int g = tid >> 5, j = tid & 31;
        const float* r = red2[g];
        float s = ((r[j] + r[j + 32]) + (r[j + 64] + r[j + 96]))
                + ((r[j + 128] + r[j + 160]) + (r[j + 192] + r[j + 224]));
        #pragma unroll
        for (int mres = 16; mres > 0; mres >>= 1) s += __shfl_xor(s, mres, 64);
        if (j == 0) red2[g][256] = s;
    }

    // depthwise conv3 + BN partial sums (waves 0-1; ph/pv ready after bar3)
    if (tid < 128) {
        float y = 0.f;
        if (tid < H) {
            float a = (tid > 0) ? ph[tid - 1] : 0.f;
            float bb = ph[tid];
            float d = (tid < H - 1) ? ph[tid + 1] : 0.f;
            y = h_w[c * 3] * a + h_w[c * 3 + 1] * bb + h_w[c * 3 + 2] * d;
            yh[(size_t)plane * H + tid] = y;
        } else if (tid >= 64 && tid < 64 + W) {
            int w = tid - 64;
            float a = (w > 0) ? pv[w - 1] : 0.f;
            float bb = pv[w];
            float d = (w < W - 1) ? pv[w + 1] : 0.f;
            y = v_w[c * 3] * a + v_w[c * 3 + 1] * bb + v_w[c * 3 + 2] * d;
            yv[(size_t)plane * W + w] = y;
        }
        float ry = wave_sum(y);
        float rys = wave_sum(y * y);
        if (tid == 0)  { atomicAdd(&acc[0 * C + c], ry); atomicAdd(&acc[1 * C + c], rys); }
        if (tid == 64) { atomicAdd(&acc[2 * C + c], ry); atomicAdd(&acc[3 * C + c], rys); }
    }
    __syncthreads();

    if (tid == 0) {
        float t = 0.f;
        #pragma unroll
        for (int a = 0; a < 6; ++a) t += sigm(red2[a][256] * (1.f / (float)HW));
        at[plane] = t * (1.f / 6.f);
        atomicAdd(&acc[4 * C + c], red2[6][256]);
        atomicAdd(&acc[5 * C + c], red2[7][256]);
    }
}

// ---------------------------------------------------------------------------
// K3: fold BN params per block and apply all four gates.
// ---------------------------------------------------------------------------
__global__ __launch_bounds__(256, 6) void k3_apply(
    const float* __restrict__ x, const float* __restrict__ f_w,
    const float* __restrict__ yh, const float* __restrict__ yv,
    const float* __restrict__ at, const float* __restrict__ acc,
    const float* __restrict__ hg, const float* __restrict__ hb,
    const float* __restrict__ vg, const float* __restrict__ vb,
    const float* __restrict__ fg, const float* __restrict__ fb,
    float* __restrict__ out)
{
    const int plane = blockIdx.x;
    const int c = plane % C;
    const int tid = threadIdx.x;
    const float* xp = x + (size_t)plane * HW;

    __shared__ __align__(16) float sx[HW];
    __shared__ __align__(16) float rm[RMROWS * W];
    __shared__ __align__(16) float av[W];
    __shared__ float ah[H];
    __shared__ float fpar[2];

    const int hrow = tid / 7;
    const int u = tid - hrow * 7;
    const int q = u * 4;
    const float inv_nh = 1.f / (float)(B * H);

    float4 Mv;
    if (tid < NU) {
        Mv = ((const float4*)xp)[tid];
        ((float4*)sx)[tid] = Mv;
    } else if (tid >= 200 && tid < 228) {
        int w = tid - 200;
        float m = acc[2 * C + c] * inv_nh;
        float v = acc[3 * C + c] * inv_nh - m * m;
        float sc = vg[c] * rsqrtf(v + 1e-5f);
        float sh = vb[c] - m * sc;
        av[w] = sigm(sc * yv[(size_t)plane * W + w] + sh);
    } else if (tid >= 228) {
        int h = tid - 228;
        float m = acc[c] * inv_nh;
        float v = acc[C + c] * inv_nh - m * m;
        float sc = hg[c] * rsqrtf(v + 1e-5f);
        float sh = hb[c] - m * sc;
        ah[h] = sigm(sc * yh[(size_t)plane * H + h] + sh);
    } else if (tid == 196) {
        const float inv_nf = 1.f / (float)(B * HW);
        float m = acc[4 * C + c] * inv_nf;
        float v = acc[5 * C + c] * inv_nf - m * m;
        float sc = fg[c] * rsqrtf(v + 1e-5f);
        fpar[0] = sc;
        fpar[1] = fb[c] - m * sc;
    }
    __syncthreads();

    if (tid < NU) {
        const float* row = sx + hrow * W;
        float4 Lv = *(const float4*)(row + (u ? q - 4 : 0));
        float4 Rv = *(const float4*)(row + (u < 6 ? q + 4 : 24));
        float4 hv = hmax13(Mv, Lv, Rv);
        *(float4*)(rm + (hrow + 3) * W + q) = hv;
        if (hrow == 0) {
            *(float4*)(rm + q) = hv;
            *(float4*)(rm + W + q) = hv;
            *(float4*)(rm + 2 * W + q) = hv;
        } else if (hrow == H - 1) {
            *(float4*)(rm + 31 * W + q) = hv;
            *(float4*)(rm + 32 * W + q) = hv;
            *(float4*)(rm + 33 * W + q) = hv;
        }
    }
    __syncthreads();

    if (tid < NU) {
        const float* vb2 = rm + hrow * W + q;
        float4 m = *(const float4*)vb2;
        m = fmax4(m, *(const float4*)(vb2 + W));
        m = fmax4(m, *(const float4*)(vb2 + 2 * W));
        m = fmax4(m, *(const float4*)(vb2 + 3 * W));
        m = fmax4(m, *(const float4*)(vb2 + 4 * W));
        m = fmax4(m, *(const float4*)(vb2 + 5 * W));
        m = fmax4(m, *(const float4*)(vb2 + 6 * W));

        const float fsc = fpar[0], fsh = fpar[1];
        const float fwc = f_w[c];
        const float ga = ah[hrow] * at[plane];
        float4 a4 = *(const float4*)(av + q);
        float4 o;
        o.x = Mv.x * ga * a4.x * sigm(fsc * ((m.x - Mv.x) * fwc) + fsh);
        o.y = Mv.y * ga * a4.y * sigm(fsc * ((m.y - Mv.y) * fwc) + fsh);
        o.z = Mv.z * ga * a4.z * sigm(fsc * ((m.z - Mv.z) * fwc) + fsh);
        o.w = Mv.w * ga * a4.w * sigm(fsc * ((m.w - Mv.w) * fwc) + fsh);
        ((float4*)(out + (size_t)plane * HW))[tid] = o;
    }
}

// ---------------------------------------------------------------------------
extern "C" void kernel_launch(void* const* d_in, const int* in_sizes, int n_in,
                              void* d_out, int out_size, void* d_ws, size_t ws_size,
                              hipStream_t stream) {
    const float* x   = (const float*)d_in[0];
    const float* h_w = (const float*)d_in[1];
    const float* h_g = (const float*)d_in[2];
    const float* h_b = (const float*)d_in[3];
    const float* v_w = (const float*)d_in[4];
    const float* v_g = (const float*)d_in[5];
    const float* v_b = (const float*)d_in[6];
    const float* f_w = (const float*)d_in[7];
    const float* f_g = (const float*)d_in[8];
    const float* f_b = (const float*)d_in[9];
    float* out = (float*)d_out;
    float* ws = (float*)d_ws;

    // workspace layout (floats)
    float* masks = ws;                 // 196*24 = 4704 (interleaved [196][6][4])
    float* acc   = ws + 4704;          // 6*576
    float* at    = ws + 8160;          // B*C
    float* yh    = ws + 81888;         // B*C*H
    float* yv    = ws + 2146272;       // B*C*W

    k0_init<<<19, 256, 0, stream>>>(masks, acc);
    k1_stats<<<NPLANE, 256, 0, stream>>>(x, h_w, v_w, f_w, masks, yh, yv, at, acc);
    k3_apply<<<NPLANE, 256, 0, stream>>>(x, f_w, yh, yv, at, acc,
                                         h_g, h_b, v_g, v_b, f_g, f_b, out);
}

// Round 5
// 233.176 us; speedup vs baseline: 3.0686x; 1.2899x over previous
//
#include <hip/hip_runtime.h>
#include <math.h>

#define B 128
#define C 576
#define H 28
#define W 28
#define HW 784
#define NPLANE (B * C)
#define RMROWS 34   // 3 ghost + 28 + 3 ghost

__device__ __forceinline__ float sigm(float z) { return 1.f / (1.f + __expf(-z)); }

__device__ __forceinline__ float4 fmax4(float4 a, float4 b) {
    a.x = fmaxf(a.x, b.x); a.y = fmaxf(a.y, b.y);
    a.z = fmaxf(a.z, b.z); a.w = fmaxf(a.w, b.w);
    return a;
}

// horizontal 7-window max for 4 px: Mv center f4, Lv left f4, Rv right f4
__device__ __forceinline__ float4 hmax13(float4 Mv, float4 Lv, float4 Rv) {
    float mm   = fmaxf(fmaxf(Mv.x, Mv.y), fmaxf(Mv.z, Mv.w));
    float l23  = fmaxf(Lv.z, Lv.w);
    float l123 = fmaxf(Lv.y, l23);
    float r01  = fmaxf(Rv.x, Rv.y);
    float r012 = fmaxf(r01, Rv.z);
    float4 o;
    o.x = fmaxf(l123, mm);
    o.y = fmaxf(l23, fmaxf(mm, Rv.x));
    o.z = fmaxf(Lv.w, fmaxf(mm, r01));
    o.w = fmaxf(mm, r012);
    return o;
}

// full 64-lane sum via DPP (VALU-only, no LDS); total lands in lane 63
__device__ __forceinline__ float dpp_sum64(float v) {
    int t;
    t = __builtin_amdgcn_update_dpp(0, __float_as_int(v), 0x111, 0xf, 0xf, true);  v += __int_as_float(t);
    t = __builtin_amdgcn_update_dpp(0, __float_as_int(v), 0x112, 0xf, 0xf, true);  v += __int_as_float(t);
    t = __builtin_amdgcn_update_dpp(0, __float_as_int(v), 0x114, 0xf, 0xf, true);  v += __int_as_float(t);
    t = __builtin_amdgcn_update_dpp(0, __float_as_int(v), 0x118, 0xf, 0xf, true);  v += __int_as_float(t);
    t = __builtin_amdgcn_update_dpp(0, __float_as_int(v), 0x142, 0xa, 0xf, false); v += __int_as_float(t);
    t = __builtin_amdgcn_update_dpp(0, __float_as_int(v), 0x143, 0xc, 0xf, false); v += __int_as_float(t);
    return v;
}

// wave-internal LDS write->read ordering (no block barrier needed: all
// producers/consumers are lanes of the same wave; DS ops complete in order,
// the fence stops compiler reordering and drains outstanding LDS ops)
__device__ __forceinline__ void wave_lds_fence() {
    asm volatile("s_waitcnt lgkmcnt(0)" ::: "memory");
    __builtin_amdgcn_sched_barrier(0);
}

// ---------------------------------------------------------------------------
// K0: zero accumulators; build orientation masks interleaved as [196][6][4].
// ---------------------------------------------------------------------------
__global__ void k0_init(float* __restrict__ masks, float* __restrict__ acc) {
    int idx = blockIdx.x * 256 + threadIdx.x;
    if (idx < 6 * C) acc[idx] = 0.f;
    if (idx < 6 * HW) {
        int a = idx / HW;
        int p = idx - a * HW;
        int r = p / W;
        int col = p - r * W;
        const float degs[6] = {0.f, 30.f, 45.f, 60.f, 90.f, 135.f};
        float t = degs[a] * 0.017453292519943295f;
        float gy = -1.f + r * (2.f / 27.f);
        float gx = -1.f + col * (2.f / 27.f);
        float perp = gx * (-sinf(t)) + gy * cosf(t);
        float z = perp * (1.f / 0.3f);
        masks[(p >> 2) * 24 + a * 4 + (p & 3)] = expf(-0.5f * z * z);
    }
}

// ---------------------------------------------------------------------------
// K1: one wave per plane. lane l<49 owns units l, l+49, l+98, l+147
//     (4 rows of one column group). No block barriers.
// ---------------------------------------------------------------------------
__global__ __launch_bounds__(256, 4) void k1_stats(
    const float* __restrict__ x,
    const float* __restrict__ h_w, const float* __restrict__ v_w,
    const float* __restrict__ f_w, const float* __restrict__ masks,
    float* __restrict__ yh, float* __restrict__ yv,
    float* __restrict__ at, float* __restrict__ acc)
{
    const int tid = threadIdx.x;
    const int wvi = tid >> 6;
    const int l   = tid & 63;
    const int plane = blockIdx.x * 4 + wvi;
    const int c = plane % C;
    const float* xp = x + (size_t)plane * HW;

    __shared__ __align__(16) float sxA[4][HW];
    __shared__ __align__(16) float rmA[4][RMROWS * W];
    __shared__ __align__(16) float cpA[4][196];
    __shared__ __align__(16) float rpA[4][196];
    float* sx = sxA[wvi];
    float* rm = rmA[wvi];
    float* cp = cpA[wvi];
    float* rp = rpA[wvi];

    const int r0 = l / 7;        // 0..6 (valid for l<49)
    const int u  = l - r0 * 7;   // column group 0..6
    const int q  = u * 4;
    const bool act = (l < 49);

    float4 Mv[4];
    float o0=0.f,o1=0.f,o2=0.f,o3=0.f,o4=0.f,o5=0.f, fs=0.f, fss=0.f;

    // P0: load x into regs + sx; per-lane col partials, row partials, orientation
    if (act) {
        float4 ca = make_float4(0.f, 0.f, 0.f, 0.f);
        float rw0, rw1, rw2, rw3;
        #pragma unroll
        for (int k = 0; k < 4; ++k) {
            const int unit = l + 49 * k;
            float4 v = ((const float4*)xp)[unit];
            Mv[k] = v;
            ((float4*)sx)[unit] = v;
            ca.x += v.x; ca.y += v.y; ca.z += v.z; ca.w += v.w;
            float rs = (v.x + v.y) + (v.z + v.w);
            if (k == 0) rw0 = rs; else if (k == 1) rw1 = rs;
            else if (k == 2) rw2 = rs; else rw3 = rs;
            const float4* mb = (const float4*)(masks + unit * 24);
            float4 m;
            m = mb[0]; o0 += v.x*m.x + v.y*m.y + v.z*m.z + v.w*m.w;
            m = mb[1]; o1 += v.x*m.x + v.y*m.y + v.z*m.z + v.w*m.w;
            m = mb[2]; o2 += v.x*m.x + v.y*m.y + v.z*m.z + v.w*m.w;
            m = mb[3]; o3 += v.x*m.x + v.y*m.y + v.z*m.z + v.w*m.w;
            m = mb[4]; o4 += v.x*m.x + v.y*m.y + v.z*m.z + v.w*m.w;
            m = mb[5]; o5 += v.x*m.x + v.y*m.y + v.z*m.z + v.w*m.w;
        }
        ((float4*)cp)[l] = ca;
        ((float4*)rp)[l] = make_float4(rw0, rw1, rw2, rw3);
    }
    wave_lds_fence();

    // P1: horizontal 7-max -> ghost-padded rm
    if (act) {
        #pragma unroll
        for (int k = 0; k < 4; ++k) {
            const int r = r0 + 7 * k;
            const float* row = sx + r * W;
            float4 Lv = *(const float4*)(row + (u ? q - 4 : 0));
            float4 Rv = *(const float4*)(row + (u < 6 ? q + 4 : 24));
            float4 hv = hmax13(Mv[k], Lv, Rv);
            *(float4*)(rm + (r + 3) * W + q) = hv;
            if (k == 0 && r0 == 0) {
                *(float4*)(rm + 0 * W + q) = hv;
                *(float4*)(rm + 1 * W + q) = hv;
                *(float4*)(rm + 2 * W + q) = hv;
            }
            if (k == 3 && r0 == 6) {
                *(float4*)(rm + 31 * W + q) = hv;
                *(float4*)(rm + 32 * W + q) = hv;
                *(float4*)(rm + 33 * W + q) = hv;
            }
        }
    }
    wave_lds_fence();

    // P2: vertical 7-max (immediate offsets into padded rm) -> spots stats
    const float fwc = f_w[c];
    if (act) {
        #pragma unroll
        for (int k = 0; k < 4; ++k) {
            const int r = r0 + 7 * k;
            const float* vb = rm + r * W + q;
            float4 m = *(const float4*)vb;
            m = fmax4(m, *(const float4*)(vb + W));
            m = fmax4(m, *(const float4*)(vb + 2 * W));
            m = fmax4(m, *(const float4*)(vb + 3 * W));
            m = fmax4(m, *(const float4*)(vb + 4 * W));
            m = fmax4(m, *(const float4*)(vb + 5 * W));
            m = fmax4(m, *(const float4*)(vb + 6 * W));
            float s0 = (m.x - Mv[k].x) * fwc;
            float s1 = (m.y - Mv[k].y) * fwc;
            float s2 = (m.z - Mv[k].z) * fwc;
            float s3 = (m.w - Mv[k].w) * fwc;
            fs  += (s0 + s1) + (s2 + s3);
            fss += (s0 * s0 + s1 * s1) + (s2 * s2 + s3 * s3);
        }
    }

    // means assembly from partials (conflict-free strided reads)
    float ph_r = 0.f;
    float4 pvv = make_float4(0.f, 0.f, 0.f, 0.f);
    if (l < 28) {
        const int rr = l % 7, kk = l / 7;
        const float* rb = rp + rr * 28 + kk;   // element (rr*7+uu)*4+kk
        float s = ((rb[0] + rb[4]) + (rb[8] + rb[12]))
                + ((rb[16] + rb[20]) + rb[24]);
        ph_r = s * (1.f / 28.f);
    }
    if (l < 7) {
        const float4* cb = (const float4*)cp;
        float4 a = cb[l];
        #pragma unroll
        for (int j = 1; j < 7; ++j) {
            float4 b = cb[l + 7 * j];
            a.x += b.x; a.y += b.y; a.z += b.z; a.w += b.w;
        }
        pvv.x = a.x * (1.f / 28.f); pvv.y = a.y * (1.f / 28.f);
        pvv.z = a.z * (1.f / 28.f); pvv.w = a.w * (1.f / 28.f);
    }

    // depthwise conv3 (zero-pad SAME) in-lane
    const float hw0 = h_w[c * 3], hw1 = h_w[c * 3 + 1], hw2 = h_w[c * 3 + 2];
    float yhv = 0.f;
    {
        float pm = __shfl_up(ph_r, 1);
        float pp = __shfl_down(ph_r, 1);
        if (l < 28) {
            float a = (l > 0) ? pm : 0.f;
            float d = (l < 27) ? pp : 0.f;
            yhv = hw0 * a + hw1 * ph_r + hw2 * d;
            yh[(size_t)plane * H + l] = yhv;
        }
    }
    const float vw0 = v_w[c * 3], vw1 = v_w[c * 3 + 1], vw2 = v_w[c * 3 + 2];
    float yvs = 0.f, yvq = 0.f;
    {
        float lf = __shfl_up(pvv.w, 1);
        float rg = __shfl_down(pvv.x, 1);
        if (l < 7) {
            float a0 = (l > 0) ? lf : 0.f;
            float d3 = (l < 6) ? rg : 0.f;
            float4 y;
            y.x = vw0 * a0    + vw1 * pvv.x + vw2 * pvv.y;
            y.y = vw0 * pvv.x + vw1 * pvv.y + vw2 * pvv.z;
            y.z = vw0 * pvv.y + vw1 * pvv.z + vw2 * pvv.w;
            y.w = vw0 * pvv.z + vw1 * pvv.w + vw2 * d3;
            ((float4*)(yv + (size_t)plane * W))[l] = y;
            yvs = (y.x + y.y) + (y.z + y.w);
            yvq = (y.x * y.x + y.y * y.y) + (y.z * y.z + y.w * y.w);
        }
    }
    float yhq = yhv * yhv;

    // 12 wave reductions, all on the VALU pipe
    o0 = dpp_sum64(o0);  o1 = dpp_sum64(o1);  o2 = dpp_sum64(o2);
    o3 = dpp_sum64(o3);  o4 = dpp_sum64(o4);  o5 = dpp_sum64(o5);
    fs = dpp_sum64(fs);  fss = dpp_sum64(fss);
    yhv = dpp_sum64(yhv); yhq = dpp_sum64(yhq);
    yvs = dpp_sum64(yvs); yvq = dpp_sum64(yvq);

    if (l == 63) {
        const float inv784 = 1.f / (float)HW;
        float t = sigm(o0 * inv784) + sigm(o1 * inv784) + sigm(o2 * inv784)
                + sigm(o3 * inv784) + sigm(o4 * inv784) + sigm(o5 * inv784);
        at[plane] = t * (1.f / 6.f);
        atomicAdd(&acc[0 * C + c], yhv);
        atomicAdd(&acc[1 * C + c], yhq);
        atomicAdd(&acc[2 * C + c], yvs);
        atomicAdd(&acc[3 * C + c], yvq);
        atomicAdd(&acc[4 * C + c], fs);
        atomicAdd(&acc[5 * C + c], fss);
    }
}

// ---------------------------------------------------------------------------
// K3: one wave per plane; BN fold + all four gates; no block barriers.
// ---------------------------------------------------------------------------
__global__ __launch_bounds__(256, 4) void k3_apply(
    const float* __restrict__ x, const float* __restrict__ f_w,
    const float* __restrict__ yh, const float* __restrict__ yv,
    const float* __restrict__ at, const float* __restrict__ acc,
    const float* __restrict__ hg, const float* __restrict__ hb,
    const float* __restrict__ vg, const float* __restrict__ vb,
    const float* __restrict__ fg, const float* __restrict__ fb,
    float* __restrict__ out)
{
    const int tid = threadIdx.x;
    const int wvi = tid >> 6;
    const int l   = tid & 63;
    const int plane = blockIdx.x * 4 + wvi;
    const int c = plane % C;
    const float* xp = x + (size_t)plane * HW;

    __shared__ __align__(16) float sxA[4][HW];
    __shared__ __align__(16) float rmA[4][RMROWS * W];
    float* sx = sxA[wvi];
    float* rm = rmA[wvi];

    const int r0 = l / 7;
    const int u  = l - r0 * 7;
    const int q  = u * 4;
    const bool act = (l < 49);

    // fold BN params (redundant per lane; broadcast loads)
    const float inv_nh = 1.f / (float)(B * H);
    const float inv_nf = 1.f / (float)(B * HW);
    float mh = acc[c] * inv_nh;
    float vh = acc[C + c] * inv_nh - mh * mh;
    float hsc = hg[c] * rsqrtf(vh + 1e-5f), hsh = hb[c] - mh * hsc;
    float mv = acc[2 * C + c] * inv_nh;
    float vv = acc[3 * C + c] * inv_nh - mv * mv;
    float vsc = vg[c] * rsqrtf(vv + 1e-5f), vsh = vb[c] - mv * vsc;
    float mf = acc[4 * C + c] * inv_nf;
    float vf = acc[5 * C + c] * inv_nf - mf * mf;
    float fsc = fg[c] * rsqrtf(vf + 1e-5f), fsh = fb[c] - mf * fsc;
    const float atv = at[plane];
    const float fwc = f_w[c];

    float4 Mv[4];
    if (act) {
        #pragma unroll
        for (int k = 0; k < 4; ++k) {
            const int unit = l + 49 * k;
            Mv[k] = ((const float4*)xp)[unit];
            ((float4*)sx)[unit] = Mv[k];
        }
    }
    wave_lds_fence();

    if (act) {
        #pragma unroll
        for (int k = 0; k < 4; ++k) {
            const int r = r0 + 7 * k;
            const float* row = sx + r * W;
            float4 Lv = *(const float4*)(row + (u ? q - 4 : 0));
            float4 Rv = *(const float4*)(row + (u < 6 ? q + 4 : 24));
            float4 hv = hmax13(Mv[k], Lv, Rv);
            *(float4*)(rm + (r + 3) * W + q) = hv;
            if (k == 0 && r0 == 0) {
                *(float4*)(rm + 0 * W + q) = hv;
                *(float4*)(rm + 1 * W + q) = hv;
                *(float4*)(rm + 2 * W + q) = hv;
            }
            if (k == 3 && r0 == 6) {
                *(float4*)(rm + 31 * W + q) = hv;
                *(float4*)(rm + 32 * W + q) = hv;
                *(float4*)(rm + 33 * W + q) = hv;
            }
        }
    }
    wave_lds_fence();

    if (act) {
        float4 yv4 = ((const float4*)(yv + (size_t)plane * W))[u];
        float4 av;
        av.x = sigm(vsc * yv4.x + vsh);
        av.y = sigm(vsc * yv4.y + vsh);
        av.z = sigm(vsc * yv4.z + vsh);
        av.w = sigm(vsc * yv4.w + vsh);
        float4* op = (float4*)(out + (size_t)plane * HW);
        #pragma unroll
        for (int k = 0; k < 4; ++k) {
            const int r = r0 + 7 * k;
            const float* vb = rm + r * W + q;
            float4 m = *(const float4*)vb;
            m = fmax4(m, *(const float4*)(vb + W));
            m = fmax4(m, *(const float4*)(vb + 2 * W));
            m = fmax4(m, *(const float4*)(vb + 3 * W));
            m = fmax4(m, *(const float4*)(vb + 4 * W));
            m = fmax4(m, *(const float4*)(vb + 5 * W));
            m = fmax4(m, *(const float4*)(vb + 6 * W));
            float ahk = sigm(hsc * yh[(size_t)plane * H + r] + hsh) * atv;
            float4 o;
            o.x = Mv[k].x * ahk * av.x * sigm(fsc * ((m.x - Mv[k].x) * fwc) + fsh);
            o.y = Mv[k].y * ahk * av.y * sigm(fsc * ((m.y - Mv[k].y) * fwc) + fsh);
            o.z = Mv[k].z * ahk * av.z * sigm(fsc * ((m.z - Mv[k].z) * fwc) + fsh);
            o.w = Mv[k].w * ahk * av.w * sigm(fsc * ((m.w - Mv[k].w) * fwc) + fsh);
            op[l + 49 * k] = o;
        }
    }
}

// ---------------------------------------------------------------------------
extern "C" void kernel_launch(void* const* d_in, const int* in_sizes, int n_in,
                              void* d_out, int out_size, void* d_ws, size_t ws_size,
                              hipStream_t stream) {
    const float* x   = (const float*)d_in[0];
    const float* h_w = (const float*)d_in[1];
    const float* h_g = (const float*)d_in[2];
    const float* h_b = (const float*)d_in[3];
    const float* v_w = (const float*)d_in[4];
    const float* v_g = (const float*)d_in[5];
    const float* v_b = (const float*)d_in[6];
    const float* f_w = (const float*)d_in[7];
    const float* f_g = (const float*)d_in[8];
    const float* f_b = (const float*)d_in[9];
    float* out = (float*)d_out;
    float* ws = (float*)d_ws;

    // workspace layout (floats)
    float* masks = ws;                 // 196*24 = 4704 (interleaved [196][6][4])
    float* acc   = ws + 4704;          // 6*576
    float* at    = ws + 8160;          // B*C
    float* yh    = ws + 81888;         // B*C*H
    float* yv    = ws + 2146272;       // B*C*W

    k0_init<<<19, 256, 0, stream>>>(masks, acc);
    k1_stats<<<NPLANE / 4, 256, 0, stream>>>(x, h_w, v_w, f_w, masks, yh, yv, at, acc);
    k3_apply<<<NPLANE / 4, 256, 0, stream>>>(x, f_w, yh, yv, at, acc,
                                             h_g, h_b, v_g, v_b, f_g, f_b, out);
}

// Round 6
// 228.438 us; speedup vs baseline: 3.1322x; 1.0207x over previous
//
#include <hip/hip_runtime.h>
#include <math.h>

#define B 128
#define C 576
#define H 28
#define W 28
#define HW 784
#define NPLANE (B * C)
#define RMROWS 34   // 3 ghost + 28 + 3 ghost

__device__ __forceinline__ float sigm(float z) { return 1.f / (1.f + __expf(-z)); }

__device__ __forceinline__ float4 fmax4(float4 a, float4 b) {
    a.x = fmaxf(a.x, b.x); a.y = fmaxf(a.y, b.y);
    a.z = fmaxf(a.z, b.z); a.w = fmaxf(a.w, b.w);
    return a;
}

// horizontal 7-window max for 4 px: Mv center f4, Lv left f4, Rv right f4
__device__ __forceinline__ float4 hmax13(float4 Mv, float4 Lv, float4 Rv) {
    float mm   = fmaxf(fmaxf(Mv.x, Mv.y), fmaxf(Mv.z, Mv.w));
    float l23  = fmaxf(Lv.z, Lv.w);
    float l123 = fmaxf(Lv.y, l23);
    float r01  = fmaxf(Rv.x, Rv.y);
    float r012 = fmaxf(r01, Rv.z);
    float4 o;
    o.x = fmaxf(l123, mm);
    o.y = fmaxf(l23, fmaxf(mm, Rv.x));
    o.z = fmaxf(Lv.w, fmaxf(mm, r01));
    o.w = fmaxf(mm, r012);
    return o;
}

// full 64-lane sum via DPP (VALU-only, no LDS); total lands in lane 63
__device__ __forceinline__ float dpp_sum64(float v) {
    int t;
    t = __builtin_amdgcn_update_dpp(0, __float_as_int(v), 0x111, 0xf, 0xf, true);  v += __int_as_float(t);
    t = __builtin_amdgcn_update_dpp(0, __float_as_int(v), 0x112, 0xf, 0xf, true);  v += __int_as_float(t);
    t = __builtin_amdgcn_update_dpp(0, __float_as_int(v), 0x114, 0xf, 0xf, true);  v += __int_as_float(t);
    t = __builtin_amdgcn_update_dpp(0, __float_as_int(v), 0x118, 0xf, 0xf, true);  v += __int_as_float(t);
    t = __builtin_amdgcn_update_dpp(0, __float_as_int(v), 0x142, 0xa, 0xf, false); v += __int_as_float(t);
    t = __builtin_amdgcn_update_dpp(0, __float_as_int(v), 0x143, 0xc, 0xf, false); v += __int_as_float(t);
    return v;
}

// wave-internal LDS write->read ordering (same-wave DS ops are in-order;
// fence stops compiler reordering and drains outstanding LDS ops)
__device__ __forceinline__ void wave_lds_fence() {
    asm volatile("s_waitcnt lgkmcnt(0)" ::: "memory");
    __builtin_amdgcn_sched_barrier(0);
}

// ---------------------------------------------------------------------------
// K0: zero accumulators; build orientation masks interleaved as [196][6][4].
// ---------------------------------------------------------------------------
__global__ void k0_init(float* __restrict__ masks, float* __restrict__ acc) {
    int idx = blockIdx.x * 256 + threadIdx.x;
    if (idx < 6 * C) acc[idx] = 0.f;
    if (idx < 6 * HW) {
        int a = idx / HW;
        int p = idx - a * HW;
        int r = p / W;
        int col = p - r * W;
        const float degs[6] = {0.f, 30.f, 45.f, 60.f, 90.f, 135.f};
        float t = degs[a] * 0.017453292519943295f;
        float gy = -1.f + r * (2.f / 27.f);
        float gx = -1.f + col * (2.f / 27.f);
        float perp = gx * (-sinf(t)) + gy * cosf(t);
        float z = perp * (1.f / 0.3f);
        masks[(p >> 2) * 24 + a * 4 + (p & 3)] = expf(-0.5f * z * z);
    }
}

// ---------------------------------------------------------------------------
// K1: one wave per plane; x staged INSIDE rm's padded rows (union buffer).
//     lane l<49 owns units l,l+49,l+98,l+147. No block barriers.
// ---------------------------------------------------------------------------
__global__ __launch_bounds__(256, 7) void k1_stats(
    const float* __restrict__ x,
    const float* __restrict__ h_w, const float* __restrict__ v_w,
    const float* __restrict__ f_w, const float* __restrict__ masks,
    float* __restrict__ yh, float* __restrict__ yv,
    float* __restrict__ at, float* __restrict__ acc)
{
    const int tid = threadIdx.x;
    const int wvi = tid >> 6;
    const int l   = tid & 63;
    const int plane = blockIdx.x * 4 + wvi;
    const int c = plane % C;
    const float* xp = x + (size_t)plane * HW;

    __shared__ __align__(16) float uA[4][RMROWS * W];   // 3.72 KB/plane
    __shared__ __align__(16) float cpA[4][196];
    __shared__ __align__(16) float rpA[4][196];
    float* rm  = uA[wvi];
    float* sxv = rm + 3 * W;      // x rows 0..27 live at padded rows 3..30
    float* cp  = cpA[wvi];
    float* rp  = rpA[wvi];

    const int r0 = l / 7;        // 0..6 (valid for l<49)
    const int u  = l - r0 * 7;   // column group 0..6
    const int q  = u * 4;
    const int qL = u ? q - 4 : 0;
    const int qR = (u < 6) ? q + 4 : 24;
    const bool act = (l < 49);

    float4 Mv[4];
    float o0=0.f,o1=0.f,o2=0.f,o3=0.f,o4=0.f,o5=0.f, fs=0.f, fss=0.f;

    // P0: load x into regs + padded LDS; col/row partials; orientation dots
    if (act) {
        float4 ca = make_float4(0.f, 0.f, 0.f, 0.f);
        float rw0, rw1, rw2, rw3;
        #pragma unroll
        for (int k = 0; k < 4; ++k) {
            const int unit = l + 49 * k;
            float4 v = ((const float4*)xp)[unit];
            Mv[k] = v;
            ((float4*)sxv)[unit] = v;
            ca.x += v.x; ca.y += v.y; ca.z += v.z; ca.w += v.w;
            float rs = (v.x + v.y) + (v.z + v.w);
            if (k == 0) rw0 = rs; else if (k == 1) rw1 = rs;
            else if (k == 2) rw2 = rs; else rw3 = rs;
            const float4* mb = (const float4*)(masks + unit * 24);
            float4 m;
            m = mb[0]; o0 += v.x*m.x + v.y*m.y + v.z*m.z + v.w*m.w;
            m = mb[1]; o1 += v.x*m.x + v.y*m.y + v.z*m.z + v.w*m.w;
            m = mb[2]; o2 += v.x*m.x + v.y*m.y + v.z*m.z + v.w*m.w;
            m = mb[3]; o3 += v.x*m.x + v.y*m.y + v.z*m.z + v.w*m.w;
            m = mb[4]; o4 += v.x*m.x + v.y*m.y + v.z*m.z + v.w*m.w;
            m = mb[5]; o5 += v.x*m.x + v.y*m.y + v.z*m.z + v.w*m.w;
        }
        ((float4*)cp)[l] = ca;
        ((float4*)rp)[l] = make_float4(rw0, rw1, rw2, rw3);
    }
    wave_lds_fence();

    // P1: horizontal 7-max; write IN PLACE over the row just read (+ ghosts).
    // Safe: within each k, reads precede writes in program order (in-order DS
    // pipe); cross-k aliasing impossible (rows differ by <7, k-steps by 7).
    if (act) {
        #pragma unroll
        for (int k = 0; k < 4; ++k) {
            const int r = r0 + 7 * k;
            const float* row = sxv + r * W;
            float4 Lv = *(const float4*)(row + qL);
            float4 Rv = *(const float4*)(row + qR);
            float4 hv = hmax13(Mv[k], Lv, Rv);
            *(float4*)(rm + (r + 3) * W + q) = hv;
            if (k == 0 && r0 == 0) {
                *(float4*)(rm + 0 * W + q) = hv;
                *(float4*)(rm + 1 * W + q) = hv;
                *(float4*)(rm + 2 * W + q) = hv;
            }
            if (k == 3 && r0 == 6) {
                *(float4*)(rm + 31 * W + q) = hv;
                *(float4*)(rm + 32 * W + q) = hv;
                *(float4*)(rm + 33 * W + q) = hv;
            }
        }
    }
    wave_lds_fence();

    // P2: vertical 7-max (immediate offsets into padded rm) -> spots stats
    const float fwc = f_w[c];
    if (act) {
        #pragma unroll
        for (int k = 0; k < 4; ++k) {
            const int r = r0 + 7 * k;
            const float* vb = rm + r * W + q;
            float4 m = *(const float4*)vb;
            m = fmax4(m, *(const float4*)(vb + W));
            m = fmax4(m, *(const float4*)(vb + 2 * W));
            m = fmax4(m, *(const float4*)(vb + 3 * W));
            m = fmax4(m, *(const float4*)(vb + 4 * W));
            m = fmax4(m, *(const float4*)(vb + 5 * W));
            m = fmax4(m, *(const float4*)(vb + 6 * W));
            float s0 = (m.x - Mv[k].x) * fwc;
            float s1 = (m.y - Mv[k].y) * fwc;
            float s2 = (m.z - Mv[k].z) * fwc;
            float s3 = (m.w - Mv[k].w) * fwc;
            fs  += (s0 + s1) + (s2 + s3);
            fss += (s0 * s0 + s1 * s1) + (s2 * s2 + s3 * s3);
        }
    }

    // means assembly from partials (conflict-free strided reads)
    float ph_r = 0.f;
    float4 pvv = make_float4(0.f, 0.f, 0.f, 0.f);
    if (l < 28) {
        const int rr = l % 7, kk = l / 7;
        const float* rb = rp + rr * 28 + kk;
        float s = ((rb[0] + rb[4]) + (rb[8] + rb[12]))
                + ((rb[16] + rb[20]) + rb[24]);
        ph_r = s * (1.f / 28.f);
    }
    if (l < 7) {
        const float4* cb = (const float4*)cp;
        float4 a = cb[l];
        #pragma unroll
        for (int j = 1; j < 7; ++j) {
            float4 b = cb[l + 7 * j];
            a.x += b.x; a.y += b.y; a.z += b.z; a.w += b.w;
        }
        pvv.x = a.x * (1.f / 28.f); pvv.y = a.y * (1.f / 28.f);
        pvv.z = a.z * (1.f / 28.f); pvv.w = a.w * (1.f / 28.f);
    }

    // depthwise conv3 (zero-pad SAME) in-lane
    const float hw0 = h_w[c * 3], hw1 = h_w[c * 3 + 1], hw2 = h_w[c * 3 + 2];
    float yhv = 0.f;
    {
        float pm = __shfl_up(ph_r, 1);
        float pp = __shfl_down(ph_r, 1);
        if (l < 28) {
            float a = (l > 0) ? pm : 0.f;
            float d = (l < 27) ? pp : 0.f;
            yhv = hw0 * a + hw1 * ph_r + hw2 * d;
            yh[(size_t)plane * H + l] = yhv;
        }
    }
    const float vw0 = v_w[c * 3], vw1 = v_w[c * 3 + 1], vw2 = v_w[c * 3 + 2];
    float yvs = 0.f, yvq = 0.f;
    {
        float lf = __shfl_up(pvv.w, 1);
        float rg = __shfl_down(pvv.x, 1);
        if (l < 7) {
            float a0 = (l > 0) ? lf : 0.f;
            float d3 = (l < 6) ? rg : 0.f;
            float4 y;
            y.x = vw0 * a0    + vw1 * pvv.x + vw2 * pvv.y;
            y.y = vw0 * pvv.x + vw1 * pvv.y + vw2 * pvv.z;
            y.z = vw0 * pvv.y + vw1 * pvv.z + vw2 * pvv.w;
            y.w = vw0 * pvv.z + vw1 * pvv.w + vw2 * d3;
            ((float4*)(yv + (size_t)plane * W))[l] = y;
            yvs = (y.x + y.y) + (y.z + y.w);
            yvq = (y.x * y.x + y.y * y.y) + (y.z * y.z + y.w * y.w);
        }
    }
    float yhq = yhv * yhv;

    // 12 wave reductions, all on the VALU pipe
    o0 = dpp_sum64(o0);  o1 = dpp_sum64(o1);  o2 = dpp_sum64(o2);
    o3 = dpp_sum64(o3);  o4 = dpp_sum64(o4);  o5 = dpp_sum64(o5);
    fs = dpp_sum64(fs);  fss = dpp_sum64(fss);
    yhv = dpp_sum64(yhv); yhq = dpp_sum64(yhq);
    yvs = dpp_sum64(yvs); yvq = dpp_sum64(yvq);

    if (l == 63) {
        const float inv784 = 1.f / (float)HW;
        float t = sigm(o0 * inv784) + sigm(o1 * inv784) + sigm(o2 * inv784)
                + sigm(o3 * inv784) + sigm(o4 * inv784) + sigm(o5 * inv784);
        at[plane] = t * (1.f / 6.f);
        atomicAdd(&acc[0 * C + c], yhv);
        atomicAdd(&acc[1 * C + c], yhq);
        atomicAdd(&acc[2 * C + c], yvs);
        atomicAdd(&acc[3 * C + c], yvq);
        atomicAdd(&acc[4 * C + c], fs);
        atomicAdd(&acc[5 * C + c], fss);
    }
}

// ---------------------------------------------------------------------------
// K3: one wave per plane; union buffer; BN fold + all four gates.
// ---------------------------------------------------------------------------
__global__ __launch_bounds__(256, 8) void k3_apply(
    const float* __restrict__ x, const float* __restrict__ f_w,
    const float* __restrict__ yh, const float* __restrict__ yv,
    const float* __restrict__ at, const float* __restrict__ acc,
    const float* __restrict__ hg, const float* __restrict__ hb,
    const float* __restrict__ vg, const float* __restrict__ vb,
    const float* __restrict__ fg, const float* __restrict__ fb,
    float* __restrict__ out)
{
    const int tid = threadIdx.x;
    const int wvi = tid >> 6;
    const int l   = tid & 63;
    const int plane = blockIdx.x * 4 + wvi;
    const int c = plane % C;
    const float* xp = x + (size_t)plane * HW;

    __shared__ __align__(16) float uA[4][RMROWS * W];
    float* rm  = uA[wvi];
    float* sxv = rm + 3 * W;

    const int r0 = l / 7;
    const int u  = l - r0 * 7;
    const int q  = u * 4;
    const int qL = u ? q - 4 : 0;
    const int qR = (u < 6) ? q + 4 : 24;
    const bool act = (l < 49);

    // fold BN params (redundant per lane; broadcast loads)
    const float inv_nh = 1.f / (float)(B * H);
    const float inv_nf = 1.f / (float)(B * HW);
    float mh = acc[c] * inv_nh;
    float vh = acc[C + c] * inv_nh - mh * mh;
    float hsc = hg[c] * rsqrtf(vh + 1e-5f), hsh = hb[c] - mh * hsc;
    float mv = acc[2 * C + c] * inv_nh;
    float vv = acc[3 * C + c] * inv_nh - mv * mv;
    float vsc = vg[c] * rsqrtf(vv + 1e-5f), vsh = vb[c] - mv * vsc;
    float mf = acc[4 * C + c] * inv_nf;
    float vf = acc[5 * C + c] * inv_nf - mf * mf;
    float fsc = fg[c] * rsqrtf(vf + 1e-5f), fsh = fb[c] - mf * fsc;
    const float atv = at[plane];
    const float fwc = f_w[c];

    float4 Mv[4];
    if (act) {
        #pragma unroll
        for (int k = 0; k < 4; ++k) {
            const int unit = l + 49 * k;
            Mv[k] = ((const float4*)xp)[unit];
            ((float4*)sxv)[unit] = Mv[k];
        }
    }
    wave_lds_fence();

    if (act) {
        #pragma unroll
        for (int k = 0; k < 4; ++k) {
            const int r = r0 + 7 * k;
            const float* row = sxv + r * W;
            float4 Lv = *(const float4*)(row + qL);
            float4 Rv = *(const float4*)(row + qR);
            float4 hv = hmax13(Mv[k], Lv, Rv);
            *(float4*)(rm + (r + 3) * W + q) = hv;
            if (k == 0 && r0 == 0) {
                *(float4*)(rm + 0 * W + q) = hv;
                *(float4*)(rm + 1 * W + q) = hv;
                *(float4*)(rm + 2 * W + q) = hv;
            }
            if (k == 3 && r0 == 6) {
                *(float4*)(rm + 31 * W + q) = hv;
                *(float4*)(rm + 32 * W + q) = hv;
                *(float4*)(rm + 33 * W + q) = hv;
            }
        }
    }
    wave_lds_fence();

    if (act) {
        float4 yv4 = ((const float4*)(yv + (size_t)plane * W))[u];
        float4 av;
        av.x = sigm(vsc * yv4.x + vsh);
        av.y = sigm(vsc * yv4.y + vsh);
        av.z = sigm(vsc * yv4.z + vsh);
        av.w = sigm(vsc * yv4.w + vsh);
        float4* op = (float4*)(out + (size_t)plane * HW);
        #pragma unroll
        for (int k = 0; k < 4; ++k) {
            const int r = r0 + 7 * k;
            const float* vb = rm + r * W + q;
            float4 m = *(const float4*)vb;
            m = fmax4(m, *(const float4*)(vb + W));
            m = fmax4(m, *(const float4*)(vb + 2 * W));
            m = fmax4(m, *(const float4*)(vb + 3 * W));
            m = fmax4(m, *(const float4*)(vb + 4 * W));
            m = fmax4(m, *(const float4*)(vb + 5 * W));
            m = fmax4(m, *(const float4*)(vb + 6 * W));
            float ahk = sigm(hsc * yh[(size_t)plane * H + r] + hsh) * atv;
            float4 o;
            o.x = Mv[k].x * ahk * av.x * sigm(fsc * ((m.x - Mv[k].x) * fwc) + fsh);
            o.y = Mv[k].y * ahk * av.y * sigm(fsc * ((m.y - Mv[k].y) * fwc) + fsh);
            o.z = Mv[k].z * ahk * av.z * sigm(fsc * ((m.z - Mv[k].z) * fwc) + fsh);
            o.w = Mv[k].w * ahk * av.w * sigm(fsc * ((m.w - Mv[k].w) * fwc) + fsh);
            op[l + 49 * k] = o;
        }
    }
}

// ---------------------------------------------------------------------------
extern "C" void kernel_launch(void* const* d_in, const int* in_sizes, int n_in,
                              void* d_out, int out_size, void* d_ws, size_t ws_size,
                              hipStream_t stream) {
    const float* x   = (const float*)d_in[0];
    const float* h_w = (const float*)d_in[1];
    const float* h_g = (const float*)d_in[2];
    const float* h_b = (const float*)d_in[3];
    const float* v_w = (const float*)d_in[4];
    const float* v_g = (const float*)d_in[5];
    const float* v_b = (const float*)d_in[6];
    const float* f_w = (const float*)d_in[7];
    const float* f_g = (const float*)d_in[8];
    const float* f_b = (const float*)d_in[9];
    float* out = (float*)d_out;
    float* ws = (float*)d_ws;

    // workspace layout (floats)
    float* masks = ws;                 // 196*24 = 4704 (interleaved [196][6][4])
    float* acc   = ws + 4704;          // 6*576
    float* at    = ws + 8160;          // B*C
    float* yh    = ws + 81888;         // B*C*H
    float* yv    = ws + 2146272;       // B*C*W

    k0_init<<<19, 256, 0, stream>>>(masks, acc);
    k1_stats<<<NPLANE / 4, 256, 0, stream>>>(x, h_w, v_w, f_w, masks, yh, yv, at, acc);
    k3_apply<<<NPLANE / 4, 256, 0, stream>>>(x, f_w, yh, yv, at, acc,
                                             h_g, h_b, v_g, v_b, f_g, f_b, out);
}